// Round 12
// baseline (377.545 us; speedup 1.0000x reference)
//
#include <hip/hip_runtime.h>

#define SS 512
#define TT 78
#define TP 80
#define NT 128        // 2 waves per block; block = ONE chain
#define NCHAIN 1024   // 512 batches x {score, alpha}
#define LN2F 0.6931471805599453f

typedef float v2f __attribute__((ext_vector_type(2)));
typedef float v4f __attribute__((ext_vector_type(4)));

template<int I> struct ic { static constexpr int v = I; };
template<int I, int N, typename F>
__device__ __forceinline__ void sfor(F f) {
    if constexpr (I < N) { f(ic<I>{}); sfor<I + 1, N>(f); }
}

// One chain per block, t-split across 2 waves (1 tag/lane, 40 live lanes/wave).
// Rationale (r2-r11): grid-level occupancy was 1 wave/SIMD — a latency trap
// where the sequential DP chain's every stall is exposed. Splitting the tag
// dimension across 2 waves doubles wave count (2048 waves = 2/SIMD) AND
// halves per-lane W storage to 40 v2f regs (no spill pressure).
__global__ __attribute__((amdgpu_flat_work_group_size(NT, NT),
                          amdgpu_waves_per_eu(2, 2)))
void crf_chain_kernel(const float* __restrict__ em,          // [B,S,T]
                      const unsigned int* __restrict__ mi32, // [B,S]
                      const float* __restrict__ st,
                      const float* __restrict__ en_,
                      const float* __restrict__ tr,          // [T,T]
                      float* __restrict__ ws)                // [NCHAIN] LSE out
{
    const int  blk      = blockIdx.x;
    const int  batch    = blk >> 1;
    const bool is_alpha = (blk & 1) != 0;
    const int  tid  = threadIdx.x;
    const int  w    = tid >> 6;
    const int  lane = tid & 63;
    const int  t    = w * 40 + lane;              // owned tag (lane < 40)
    const bool live = (lane < 40) && (t < TT);
    const int  tc   = live ? t : (TT - 1);        // clamped for safe loads

    __shared__ __align__(16) float sE[2][TP];     // double-buffered E vector
    __shared__ float sMax[2][2];                  // per-wave max of E, dbuf
    __shared__ float sFin[2];
    __shared__ int sflag;

    // ---- mask layout detection (int32 vs byte bools) ----
    if (tid == 0) sflag = 1;
    __syncthreads();
    { bool ok = true;
      for (int k = tid; k < 512; k += NT) ok = ok && (mi32[k] <= 1u);
      if (!ok) atomicAnd(&sflag, 0); }
    __syncthreads();
    const bool mask_int = (sflag != 0);
    const unsigned char* mi8 = (const unsigned char*)mi32;

    // ---- W column for my tag: Wp[p] = {exp(tr[2p][tc]), exp(tr[2p+1][tc])} ----
    v2f Wp[TP / 2];                                // 40 v2f = 80 VGPRs
    sfor<0, TP / 2>([&](auto P) {
        constexpr int p = decltype(P)::v;
        constexpr int j0 = 2 * p, j1 = 2 * p + 1;
        float w0 = (j0 < TT) ? __expf(tr[j0 * TT + tc]) : 0.f;
        float w1 = (j1 < TT) ? __expf(tr[j1 * TT + tc]) : 0.f;
        asm volatile("" : "+v"(w0), "+v"(w1));     // anti-remat fence (locals)
        Wp[p] = (v2f){w0, w1};
    });

    // ---- linear-domain init: E = exp(start + em0), M2 = 0 ----
    const size_t base = (size_t)batch * SS * TT;
    float e = live ? __expf(st[tc] + em[base + tc]) : 0.f;
    int M2 = 0;

    if (lane < 40) sE[0][t] = e;                  // tags 0..79 covered exactly
    float nm = e;
    #pragma unroll
    for (int o = 32; o > 0; o >>= 1) nm = fmaxf(nm, __shfl_xor(nm, o));
    if (lane == 0) sMax[0][w] = nm;

    // prefetch step 1 (exp off the critical path)
    const float* rp = em + base + TT;
    float EmN = __expf(rp[tc]);
    unsigned mk_n = mask_int ? mi32[batch * SS + 1]
                             : (unsigned)mi8[batch * SS + 1];
    __syncthreads();

    for (int i = 1; i < SS; ++i) {
        const int cur = (i - 1) & 1, nxt = i & 1;
        const float Em = EmN;
        const unsigned mki = mk_n;
        if (i + 1 < SS) {
            rp += TT;
            EmN = __expf(rp[tc]);
            mk_n = mask_int ? mi32[batch * SS + i + 1]
                            : (unsigned)mi8[batch * SS + i + 1];
        }

        // shared, deterministic pow2 renorm factor from stored E's max
        float m = fmaxf(sMax[cur][0], sMax[cur][1]);
        int d2 = (int)((__float_as_uint(m) >> 23) & 0xFF) - 127;
        d2 = d2 < -60 ? -60 : (d2 > 60 ? 60 : d2);
        float scl = __uint_as_float((unsigned)(127 - d2) << 23);

        // v[t] = sum_j E[j] * W[j][t]  (broadcast reads, 40 pk-FMA)
        const v4f* ep = (const v4f*)sE[cur];
        v2f a0{0.f, 0.f}, a1{0.f, 0.f};
        sfor<0, TP / 4>([&](auto K) {
            constexpr int k = decltype(K)::v;
            v4f x = ep[k];
            a0 = __builtin_elementwise_fma((v2f){x.x, x.y}, Wp[2 * k],     a0);
            a1 = __builtin_elementwise_fma((v2f){x.z, x.w}, Wp[2 * k + 1], a1);
        });
        v2f va = a0 + a1;
        float v = va.x + va.y;
        float n = live ? v * scl * Em : 0.f;

        const bool upd = is_alpha | (mki != 0);
        if (upd) { e = n; M2 += d2; }             // both waves agree on d2/upd

        float lm = e;                              // per-wave max of new E
        #pragma unroll
        for (int o = 32; o > 0; o >>= 1) lm = fmaxf(lm, __shfl_xor(lm, o));

        if (lane < 40) sE[nxt][t] = e;            // write OTHER buffer
        if (lane == 0) sMax[nxt][w] = lm;
        __syncthreads();                           // single barrier per step
    }

    // ---- final: ln(sum_t E[t]*exp(end[t])) + M2*ln2 ----
    float fs = live ? e * __expf(en_[tc]) : 0.f;
    #pragma unroll
    for (int o = 32; o > 0; o >>= 1) fs += __shfl_xor(fs, o);
    if (lane == 0) sFin[w] = fs;
    __syncthreads();
    if (tid == 0) ws[blk] = __logf(sFin[0] + sFin[1]) + (float)M2 * LN2F;
}

__global__ void combine_kernel(const float* __restrict__ ws,
                               float* __restrict__ out) {
    int b = blockIdx.x * 256 + threadIdx.x;
    if (b < 512) out[b] = ws[2 * b + 1] - ws[2 * b];   // alpha - score
}

extern "C" void kernel_launch(void* const* d_in, const int* in_sizes, int n_in,
                              void* d_out, int out_size, void* d_ws, size_t ws_size,
                              hipStream_t stream) {
    const float* emissions    = (const float*)d_in[0];
    const unsigned int* mask  = (const unsigned int*)d_in[1];
    const float* start_trans  = (const float*)d_in[2];
    const float* end_trans    = (const float*)d_in[3];
    const float* transitions  = (const float*)d_in[4];
    float* ws  = (float*)d_ws;           // NCHAIN floats of scratch
    float* out = (float*)d_out;

    crf_chain_kernel<<<NCHAIN, NT, 0, stream>>>(emissions, mask, start_trans,
                                                end_trans, transitions, ws);
    combine_kernel<<<2, 256, 0, stream>>>(ws, out);
}

// Round 13
// 297.314 us; speedup vs baseline: 1.2699x; 1.2699x over previous
//
#include <hip/hip_runtime.h>

#define BB 512
#define SS 512
#define TT 78
#define TP 80      // padded tag count
#define NT 128     // 2 waves: wave0 = score chain, wave1 = alpha chain
#define LN2F 0.6931471805599453f

typedef _Float16 v2h __attribute__((ext_vector_type(2)));

template<int I> struct ic { static constexpr int v = I; };
template<int I, int N, typename F>
__device__ __forceinline__ void sfor(F f) {
    if constexpr (I < N) { f(ic<I>{}); sfor<I + 1, N>(f); }
}

__device__ __forceinline__ unsigned short f16b(float x) {
    return __builtin_bit_cast(unsigned short, (_Float16)x);
}

// one DPP-shifted fmax step (ctrl must be a compile-time constant)
template<int CTRL>
__device__ __forceinline__ float dppmax(float v) {
    int vi = __builtin_bit_cast(int, v);
    int sh = __builtin_amdgcn_update_dpp(vi, vi, CTRL, 0xf, 0xf, false);
    return fmaxf(v, __builtin_bit_cast(float, sh));
}
// full 64-lane max via DPP (VALU-speed; ~60cyc vs ~300 for shfl_xor chain)
__device__ __forceinline__ float wave_max_dpp(float v) {
    v = dppmax<0x111>(v);   // row_shr:1
    v = dppmax<0x112>(v);   // row_shr:2
    v = dppmax<0x114>(v);   // row_shr:4
    v = dppmax<0x118>(v);   // row_shr:8   -> lane 15/31/47/63 = row max
    v = dppmax<0x142>(v);   // row_bcast15 -> lane31=max(r0,r1), lane63=max(r2,r3)
    v = dppmax<0x143>(v);   // row_bcast31 -> lane63 = full max
    int m = __builtin_amdgcn_readlane(__builtin_bit_cast(int, v), 63);
    return __builtin_bit_cast(float, m);
}

// Design (r13): zero-spill AND zero-barrier. r12 proved VGPR readings real
// (88 there) => r2-r11 (demand>160) truly spilled; r12's barriers cost the
// same ~600cyc the spill did (975 vs 940 cyc/chain-step). This kernel pays
// neither: full f16 datapath shrinks W to 80 VGPRs (demand ~125, fits), one
// chain per wave (no __syncthreads in loop), pk_fma_f16 full-rate math,
// DPP wave-max renorm keeps f16 in range.
__global__ __attribute__((amdgpu_flat_work_group_size(NT, NT),
                          amdgpu_waves_per_eu(1, 1)))
void crf_fwd_kernel(const float* __restrict__ em,          // [B,S,T]
                    const unsigned int* __restrict__ mi32, // [B,S]
                    const float* __restrict__ st,
                    const float* __restrict__ en_,
                    const float* __restrict__ tr,          // [T,T]
                    float* __restrict__ out)               // [B]
{
    const int b    = blockIdx.x;
    const int tid  = threadIdx.x;
    const int w    = tid >> 6;            // 0 = score (masked), 1 = alpha
    const int lane = tid & 63;
    const bool has2 = lane < (TT - 64);
    const int  t0  = lane;
    const int  t1c = has2 ? (lane + 64) : (TT - 1);

    __shared__ __align__(16) unsigned short sEh[2][TP];  // E (f16), per chain
    __shared__ float sfin[2];
    __shared__ int sflag;

    // ---- mask layout detection (int32 vs byte bools) ----
    if (tid == 0) sflag = 1;
    __syncthreads();
    { bool ok = true;
      for (int k = tid; k < 512; k += NT) ok = ok && (mi32[k] <= 1u);
      if (!ok) atomicAnd(&sflag, 0); }
    __syncthreads();
    const bool mask_int = (sflag != 0);
    const unsigned char* mi8 = (const unsigned char*)mi32;
    const bool is_alpha = (w == 1);

    // ---- W = exp(trans) as packed f16 pairs: 80 VGPRs total ----
    unsigned wt0[TP / 2], wt1[TP / 2];
    sfor<0, TP / 2>([&](auto P) {
        constexpr int p = decltype(P)::v;
        constexpr int j0 = 2 * p, j1 = 2 * p + 1;
        float a0 = (j0 < TT) ? __expf(tr[j0 * TT + t0])  : 0.f;
        float a1 = (j1 < TT) ? __expf(tr[j1 * TT + t0])  : 0.f;
        float b0 = (j0 < TT) ? __expf(tr[j0 * TT + t1c]) : 0.f;
        float b1 = (j1 < TT) ? __expf(tr[j1 * TT + t1c]) : 0.f;
        unsigned pa = (unsigned)f16b(a0) | ((unsigned)f16b(a1) << 16);
        unsigned pb = (unsigned)f16b(b0) | ((unsigned)f16b(b1) << 16);
        asm volatile("" : "+v"(pa), "+v"(pb));   // anti-remat fence (locals)
        wt0[p] = pa; wt1[p] = pb;
    });

    // ---- init: E = exp(start+em0), normalized so wave-max ~ [0.5,1] ----
    const size_t base = (size_t)b * SS * TT;
    float e0 = __expf(st[t0]  + em[base + t0]);
    float e1 = __expf(st[t1c] + em[base + t1c]);
    {
        float mx = wave_max_dpp(fmaxf(e0, has2 ? e1 : 0.f));
        int d2 = (int)((__float_as_uint(mx) >> 23) & 0xFF) - 127;
        float scl = __uint_as_float((unsigned)(127 - d2) << 23);
        e0 *= scl; e1 *= scl;
        // M2 init below
        sEh[w][lane] = f16b(e0);
        if (has2) sEh[w][64 + lane] = f16b(e1);
        if (lane == 14 || lane == 15) sEh[w][64 + lane] = 0;  // pads 78,79
        // stash d2 in e1's M2 slot:
        sfin[w] = (float)d2;   // temp reuse, read immediately below by own wave
    }
    int M2 = (int)sfin[w];

    // ---- prefetch step 1 ----
    const float* rp = em + base + TT;
    float EmN0 = __expf(rp[t0]);
    float EmN1 = __expf(rp[t1c]);
    unsigned mk_n = mask_int ? mi32[b * SS + 1] : (unsigned)mi8[b * SS + 1];

    for (int i = 1; i < SS; ++i) {
        const float Em0 = EmN0, Em1 = EmN1;
        const unsigned mki = mk_n;
        if (i + 1 < SS) {
            rp += TT;
            EmN0 = __expf(rp[t0]);
            EmN1 = __expf(rp[t1c]);
            mk_n = mask_int ? mi32[b * SS + i + 1] : (unsigned)mi8[b * SS + i + 1];
        }
        __builtin_amdgcn_wave_barrier();

        // ---- dot: v[t] = sum_j E[j]*W[j][t], f16 packed math ----
        const uint4* ep = (const uint4*)sEh[w];
        v2h h0a{0, 0}, h0b{0, 0}, h1a{0, 0}, h1b{0, 0};
        sfor<0, TP / 8>([&](auto K) {
            constexpr int k = decltype(K)::v;
            uint4 q = ep[k];
            sfor<0, 4>([&](auto J) {
                constexpr int j = decltype(J)::v;
                constexpr int p = 4 * k + j;
                unsigned uq = (j == 0) ? 0u : 0u;  // placeholder (replaced below)
                (void)uq;
                unsigned u = (j == 0) ? q.x : (j == 1) ? q.y : (j == 2) ? q.z : q.w;
                v2h x  = __builtin_bit_cast(v2h, u);
                v2h w0 = __builtin_bit_cast(v2h, wt0[p]);
                v2h w1 = __builtin_bit_cast(v2h, wt1[p]);
                if constexpr ((p & 1) == 0) {
                    h0a = __builtin_elementwise_fma(x, w0, h0a);
                    h1a = __builtin_elementwise_fma(x, w1, h1a);
                } else {
                    h0b = __builtin_elementwise_fma(x, w0, h0b);
                    h1b = __builtin_elementwise_fma(x, w1, h1b);
                }
            });
        });
        v2h s0 = h0a + h0b, s1 = h1a + h1b;
        float v0 = (float)s0.x + (float)s0.y;
        float v1 = (float)s1.x + (float)s1.y;

        float n0 = v0 * Em0;
        float n1 = v1 * Em1;

        // renorm by wave max (keeps stored f16 <= 1; exact pow2)
        float mx = wave_max_dpp(fmaxf(n0, has2 ? n1 : 0.f));
        int d2 = (int)((__float_as_uint(mx) >> 23) & 0xFF) - 127;
        float scl = __uint_as_float((unsigned)(127 - d2) << 23);

        const bool upd = is_alpha | (mki != 0);
        e0 = upd ? n0 * scl : e0;
        e1 = upd ? n1 * scl : e1;
        M2 = upd ? M2 + d2 : M2;

        __builtin_amdgcn_wave_barrier();
        sEh[w][lane] = f16b(e0);
        if (has2) sEh[w][64 + lane] = f16b(e1);
    }

    // ---- final: ln(sum_t E[t]*exp(end[t])) + M2*ln2 ----
    float fs = e0 * __expf(en_[t0]);
    if (has2) fs += e1 * __expf(en_[t1c]);
    #pragma unroll
    for (int o = 32; o > 0; o >>= 1) fs += __shfl_xor(fs, o);
    __syncthreads();   // sfin temp (init d2) is done; safe to overwrite
    if (lane == 0) sfin[w] = __logf(fs) + (float)M2 * LN2F;
    __syncthreads();
    if (tid == 0) out[b] = sfin[1] - sfin[0];   // partition - score
}

extern "C" void kernel_launch(void* const* d_in, const int* in_sizes, int n_in,
                              void* d_out, int out_size, void* d_ws, size_t ws_size,
                              hipStream_t stream) {
    const float* emissions    = (const float*)d_in[0];
    const unsigned int* mask  = (const unsigned int*)d_in[1];
    const float* start_trans  = (const float*)d_in[2];
    const float* end_trans    = (const float*)d_in[3];
    const float* transitions  = (const float*)d_in[4];
    float* out = (float*)d_out;

    crf_fwd_kernel<<<BB, NT, 0, stream>>>(emissions, mask, start_trans,
                                          end_trans, transitions, out);
}